// Round 1
// baseline (743.219 us; speedup 1.0000x reference)
//
#include <hip/hip_runtime.h>
#include <hip/hip_bf16.h>
#include <cstdint>

typedef short bf16x8 __attribute__((ext_vector_type(8)));
typedef float f32x4 __attribute__((ext_vector_type(4)));

constexpr int Bn = 64, Hn = 56, Wn = 56, Cn = 128, Ln = 3136;
constexpr int NWIN = 4096;          // 64 imgs * 8*8 windows
constexpr int NTOK = 49;            // 7*7
constexpr int Mtot = NWIN * NTOK;   // 200704
constexpr int HID = 384;
constexpr int SHIFT_ = 3;

__device__ __forceinline__ float bf2f(short s) {
  union { uint32_t u; float f; } c; c.u = ((uint32_t)(uint16_t)s) << 16; return c.f;
}
__device__ __forceinline__ short f2bf(float f) {
  union { float f; uint32_t u; } c; c.f = f;
  uint32_t r = (c.u + 0x7FFFu + ((c.u >> 16) & 1u)) >> 16;
  return (short)r;
}
__device__ __forceinline__ float wred(float v) {
  #pragma unroll
  for (int o = 32; o > 0; o >>= 1) v += __shfl_xor(v, o);
  return v;
}

// ---------------- weight f32 -> bf16 ----------------
__global__ void k_cvt(const float* __restrict__ s, short* __restrict__ d, int n) {
  int i = blockIdx.x * 256 + threadIdx.x;
  if (i < n) d[i] = f2bf(s[i]);
}

// ---------------- LN1 + roll(-3,-3) + window partition (gather) ----------------
// out row r = window-major token row; source row gathered from x.
__global__ __launch_bounds__(256) void k_ln1(const float* __restrict__ x,
                                             const float* __restrict__ g,
                                             const float* __restrict__ be,
                                             short* __restrict__ out) {
  int wave = threadIdx.x >> 6, lane = threadIdx.x & 63;
  int row = blockIdx.x * 4 + wave;
  int win = row / NTOK, tok = row % NTOK;
  int b = win >> 6, wi = win & 63;
  int wh = wi >> 3, ww = wi & 7;
  int hr = wh * 7 + tok / 7;
  int wr = ww * 7 + tok % 7;
  int hs = hr + SHIFT_; if (hs >= Hn) hs -= Hn;   // roll -3: out[i]=in[i+3]
  int ws2 = wr + SHIFT_; if (ws2 >= Wn) ws2 -= Wn;
  const float* xr = x + (size_t)(b * Ln + hs * Wn + ws2) * Cn;
  float2 v = *(const float2*)(xr + lane * 2);
  float sum = wred(v.x + v.y);
  float sq  = wred(v.x * v.x + v.y * v.y);
  float mean = sum * (1.f / Cn);
  float var  = sq * (1.f / Cn) - mean * mean;
  float rstd = rsqrtf(var + 1e-5f);
  int c0 = lane * 2;
  short2 o;
  o.x = f2bf((v.x - mean) * rstd * g[c0]     + be[c0]);
  o.y = f2bf((v.y - mean) * rstd * g[c0 + 1] + be[c0 + 1]);
  *(short2*)(out + (size_t)row * Cn + c0) = o;
}

// ---------------- LN2 (plain rows, reads f32 h from d_out) ----------------
__global__ __launch_bounds__(256) void k_ln2(const float* __restrict__ h,
                                             const float* __restrict__ g,
                                             const float* __restrict__ be,
                                             short* __restrict__ out) {
  int wave = threadIdx.x >> 6, lane = threadIdx.x & 63;
  int row = blockIdx.x * 4 + wave;
  const float* xr = h + (size_t)row * Cn;
  float2 v = *(const float2*)(xr + lane * 2);
  float sum = wred(v.x + v.y);
  float sq  = wred(v.x * v.x + v.y * v.y);
  float mean = sum * (1.f / Cn);
  float var  = sq * (1.f / Cn) - mean * mean;
  float rstd = rsqrtf(var + 1e-5f);
  int c0 = lane * 2;
  short2 o;
  o.x = f2bf((v.x - mean) * rstd * g[c0]     + be[c0]);
  o.y = f2bf((v.y - mean) * rstd * g[c0 + 1] + be[c0 + 1]);
  *(short2*)(out + (size_t)row * Cn + c0) = o;
}

// ---------------- generic tall GEMM: C[M][N] = A[M][K] @ W[N][K]^T + bias ----------------
// EPI: 0 = qkv scatter (bf16), 1 = proj + un-window + roll(+3,+3) + residual (f32),
//      2 = exact GELU (bf16), 3 = final: out += v (f32, out holds h)
constexpr int LDW = 24;  // LDS row pad (bf16 elems): stride 16B-aligned, banks spread
template<int K, int NTOT, int EPI>
__global__ __launch_bounds__(256) void k_gemm(const short* __restrict__ A,
                                              const short* __restrict__ W,
                                              const float* __restrict__ bias,
                                              const float* __restrict__ aux,
                                              float* __restrict__ outF,
                                              short* __restrict__ outB) {
  __shared__ __attribute__((aligned(16))) short ldsW[64][K + LDW];
  const int t = threadIdx.x;
  const int wave = t >> 6, lane = t & 63;
  const int m_base = blockIdx.x * 64 + wave * 16;
  const int ar = m_base + (lane & 15);
  const int kb = (lane >> 4) * 8;

  bf16x8 af[K / 32];
  #pragma unroll
  for (int s = 0; s < K / 32; ++s)
    af[s] = *(const bf16x8*)(A + (size_t)ar * K + s * 32 + kb);

  for (int nb = 0; nb < NTOT / 64; ++nb) {
    __syncthreads();
    constexpr int LPR = K / 8;
    #pragma unroll
    for (int i = 0; i < 64 * LPR / 256; ++i) {
      int idx = i * 256 + t;
      int n = idx / LPR, kk = (idx % LPR) * 8;
      *(bf16x8*)(&ldsW[n][kk]) = *(const bf16x8*)(W + (size_t)(nb * 64 + n) * K + kk);
    }
    __syncthreads();

    f32x4 acc[4];
    #pragma unroll
    for (int tt = 0; tt < 4; ++tt) acc[tt] = (f32x4){0.f, 0.f, 0.f, 0.f};
    #pragma unroll
    for (int s = 0; s < K / 32; ++s) {
      #pragma unroll
      for (int tt = 0; tt < 4; ++tt) {
        bf16x8 bfr = *(const bf16x8*)(&ldsW[tt * 16 + (lane & 15)][s * 32 + kb]);
        acc[tt] = __builtin_amdgcn_mfma_f32_16x16x32_bf16(af[s], bfr, acc[tt], 0, 0, 0);
      }
    }

    #pragma unroll
    for (int tt = 0; tt < 4; ++tt) {
      #pragma unroll
      for (int r = 0; r < 4; ++r) {
        int m = m_base + (lane >> 4) * 4 + r;   // D row = (lane>>4)*4 + reg
        int col = nb * 64 + tt * 16 + (lane & 15);  // D col = lane&15
        float v = acc[tt][r] + bias[col];
        if (EPI == 0) {
          int win = m / NTOK, tok = m % NTOK;
          int qi = col >> 7, cc = col & 127;
          outB[(((size_t)win * 3 + qi) * NTOK + tok) * Cn + cc] = f2bf(v);
        } else if (EPI == 1) {
          int win = m / NTOK, tok = m % NTOK;
          int b = win >> 6, wi = win & 63;
          int hr = (wi >> 3) * 7 + tok / 7 + SHIFT_; if (hr >= Hn) hr -= Hn;
          int wr = (wi & 7) * 7 + tok % 7 + SHIFT_;  if (wr >= Wn) wr -= Wn;
          size_t dst = (size_t)(b * Ln + hr * Wn + wr) * Cn + col;
          outF[dst] = aux[dst] + v;            // h = shortcut + o
        } else if (EPI == 2) {
          float gg = 0.5f * v * (1.f + erff(v * 0.70710678f));
          outB[(size_t)m * NTOT + col] = f2bf(gg);
        } else {
          size_t dst = (size_t)m * Cn + col;
          outF[dst] = outF[dst] + v;           // out = h + mlp
        }
      }
    }
  }
}

// ---------------- per-window attention: QK^T, softmax, PV ----------------
__global__ __launch_bounds__(256) void k_attn(const short* __restrict__ qkv,
                                              short* __restrict__ out) {
  __shared__ __attribute__((aligned(16))) short sQKV[3 * NTOK * Cn];  // 37632 B
  __shared__ float sS[4 * NTOK * NTOK];                               // 38416 B
  const int t = threadIdx.x;
  const int win = blockIdx.x;
  const short* src = qkv + (size_t)win * 3 * NTOK * Cn;
  for (int i = t; i < 3 * NTOK * Cn / 8; i += 256)
    ((bf16x8*)sQKV)[i] = ((const bf16x8*)src)[i];
  __syncthreads();

  // scores = q @ k^T * d^-0.5
  for (int idx = t; idx < 4 * NTOK * NTOK; idx += 256) {
    int hh = idx / (NTOK * NTOK);
    int rem = idx % (NTOK * NTOK);
    int i = rem / NTOK, j = rem % NTOK;
    const short* qp = sQKV + (size_t)i * Cn + hh * 32;
    const short* kp = sQKV + (size_t)(NTOK + j) * Cn + hh * 32;
    float s = 0.f;
    #pragma unroll
    for (int e = 0; e < 4; ++e) {
      bf16x8 qv = *(const bf16x8*)(qp + e * 8);
      bf16x8 kv = *(const bf16x8*)(kp + e * 8);
      #pragma unroll
      for (int u = 0; u < 8; ++u) s += bf2f(qv[u]) * bf2f(kv[u]);
    }
    sS[idx] = s * 0.17677669529663687f;   // 1/sqrt(32)
  }
  __syncthreads();

  // softmax over j (49) per (head,row)
  for (int row = t; row < 4 * NTOK; row += 256) {
    float* p = sS + (size_t)row * NTOK;
    float mx = -1e30f;
    for (int j = 0; j < NTOK; ++j) mx = fmaxf(mx, p[j]);
    float sum = 0.f;
    for (int j = 0; j < NTOK; ++j) { float e = __expf(p[j] - mx); p[j] = e; sum += e; }
    float inv = 1.f / sum;
    for (int j = 0; j < NTOK; ++j) p[j] *= inv;
  }
  __syncthreads();

  // o[i][c] = sum_j p[h(c)][i][j] * v[j][c], 8-wide chunks over c
  for (int idx = t; idx < NTOK * 16; idx += 256) {
    int i = idx >> 4, cb = (idx & 15) * 8;
    int hh = cb >> 5;
    const float* p = sS + (size_t)(hh * NTOK + i) * NTOK;
    const short* vp = sQKV + 2 * NTOK * Cn + cb;
    float acc[8];
    #pragma unroll
    for (int u = 0; u < 8; ++u) acc[u] = 0.f;
    for (int j = 0; j < NTOK; ++j) {
      float pj = p[j];
      bf16x8 vv = *(const bf16x8*)(vp + (size_t)j * Cn);
      #pragma unroll
      for (int u = 0; u < 8; ++u) acc[u] += pj * bf2f(vv[u]);
    }
    bf16x8 ov;
    #pragma unroll
    for (int u = 0; u < 8; ++u) ov[u] = f2bf(acc[u]);
    *(bf16x8*)(out + ((size_t)win * NTOK + i) * Cn + cb) = ov;
  }
}

extern "C" void kernel_launch(void* const* d_in, const int* in_sizes, int n_in,
                              void* d_out, int out_size, void* d_ws, size_t ws_size,
                              hipStream_t stream) {
  const float* x     = (const float*)d_in[0];
  const float* g1    = (const float*)d_in[1];
  const float* be1   = (const float*)d_in[2];
  const float* Wqkv  = (const float*)d_in[3];
  const float* bqkv  = (const float*)d_in[4];
  const float* Wproj = (const float*)d_in[5];
  const float* bproj = (const float*)d_in[6];
  const float* g2    = (const float*)d_in[7];
  const float* be2   = (const float*)d_in[8];
  const float* Wm1   = (const float*)d_in[9];
  const float* bm1   = (const float*)d_in[10];
  const float* Wm2   = (const float*)d_in[11];
  const float* bm2   = (const float*)d_in[12];
  float* out = (float*)d_out;

  char* ws = (char*)d_ws;
  size_t SA = (size_t)Mtot * Cn * 2;    // 51.4 MB: ln1win / attn_out / ln2
  size_t SB = (size_t)Mtot * HID * 2;   // 154.1 MB: qkv / m1act
  short* bufA = (short*)ws;
  short* bufB = (short*)(ws + SA);
  short* wq = (short*)(ws + SA + SB);
  short* wp = wq + 384 * 128;
  short* w1 = wp + 128 * 128;
  short* w2 = w1 + 384 * 128;

  k_cvt<<<192, 256, 0, stream>>>(Wqkv, wq, 49152);
  k_cvt<<<64, 256, 0, stream>>>(Wproj, wp, 16384);
  k_cvt<<<192, 256, 0, stream>>>(Wm1, w1, 49152);
  k_cvt<<<192, 256, 0, stream>>>(Wm2, w2, 49152);

  k_ln1<<<Mtot / 4, 256, 0, stream>>>(x, g1, be1, bufA);
  k_gemm<128, 384, 0><<<Mtot / 64, 256, 0, stream>>>(bufA, wq, bqkv, nullptr, nullptr, bufB);
  k_attn<<<NWIN, 256, 0, stream>>>(bufB, bufA);
  k_gemm<128, 128, 1><<<Mtot / 64, 256, 0, stream>>>(bufA, wp, bproj, x, out, nullptr);
  k_ln2<<<Mtot / 4, 256, 0, stream>>>(out, g2, be2, bufA);
  k_gemm<128, 384, 2><<<Mtot / 64, 256, 0, stream>>>(bufA, w1, bm1, nullptr, nullptr, bufB);
  k_gemm<384, 128, 3><<<Mtot / 64, 256, 0, stream>>>(bufB, w2, bm2, nullptr, out, nullptr);
}

// Round 3
// 425.905 us; speedup vs baseline: 1.7450x; 1.7450x over previous
//
#include <hip/hip_runtime.h>
#include <hip/hip_bf16.h>
#include <cstdint>

typedef short bf16x8 __attribute__((ext_vector_type(8)));
typedef float f32x4 __attribute__((ext_vector_type(4)));

constexpr int Bn = 64, Hn = 56, Wn = 56, Cn = 128, Ln = 3136;
constexpr int NWIN = 4096;          // 64 imgs * 8*8 windows
constexpr int NTOK = 49;            // 7*7
constexpr int Mtot = NWIN * NTOK;   // 200704
constexpr int HID = 384;
constexpr int SHIFT_ = 3;

__device__ __forceinline__ float bf2f(short s) {
  union { uint32_t u; float f; } c; c.u = ((uint32_t)(uint16_t)s) << 16; return c.f;
}
__device__ __forceinline__ short f2bf(float f) {
  union { float f; uint32_t u; } c; c.f = f;
  uint32_t r = (c.u + 0x7FFFu + ((c.u >> 16) & 1u)) >> 16;
  return (short)r;
}
__device__ __forceinline__ float wred(float v) {
  #pragma unroll
  for (int o = 32; o > 0; o >>= 1) v += __shfl_xor(v, o);
  return v;
}

// ---------------- weight f32 -> bf16 ----------------
__global__ void k_cvt(const float* __restrict__ s, short* __restrict__ d, int n) {
  int i = blockIdx.x * 256 + threadIdx.x;
  if (i < n) d[i] = f2bf(s[i]);
}

// ---------------- LN1 + roll(-3,-3) + window partition (gather) ----------------
__global__ __launch_bounds__(256) void k_ln1(const float* __restrict__ x,
                                             const float* __restrict__ g,
                                             const float* __restrict__ be,
                                             short* __restrict__ out) {
  int wave = threadIdx.x >> 6, lane = threadIdx.x & 63;
  int row = blockIdx.x * 4 + wave;
  int win = row / NTOK, tok = row % NTOK;
  int b = win >> 6, wi = win & 63;
  int wh = wi >> 3, ww = wi & 7;
  int hr = wh * 7 + tok / 7;
  int wr = ww * 7 + tok % 7;
  int hs = hr + SHIFT_; if (hs >= Hn) hs -= Hn;
  int ws2 = wr + SHIFT_; if (ws2 >= Wn) ws2 -= Wn;
  const float* xr = x + (size_t)(b * Ln + hs * Wn + ws2) * Cn;
  float2 v = *(const float2*)(xr + lane * 2);
  float sum = wred(v.x + v.y);
  float sq  = wred(v.x * v.x + v.y * v.y);
  float mean = sum * (1.f / Cn);
  float var  = sq * (1.f / Cn) - mean * mean;
  float rstd = rsqrtf(var + 1e-5f);
  int c0 = lane * 2;
  short2 o;
  o.x = f2bf((v.x - mean) * rstd * g[c0]     + be[c0]);
  o.y = f2bf((v.y - mean) * rstd * g[c0 + 1] + be[c0 + 1]);
  *(short2*)(out + (size_t)row * Cn + c0) = o;
}

// ---------------- LN2 ----------------
__global__ __launch_bounds__(256) void k_ln2(const float* __restrict__ h,
                                             const float* __restrict__ g,
                                             const float* __restrict__ be,
                                             short* __restrict__ out) {
  int wave = threadIdx.x >> 6, lane = threadIdx.x & 63;
  int row = blockIdx.x * 4 + wave;
  const float* xr = h + (size_t)row * Cn;
  float2 v = *(const float2*)(xr + lane * 2);
  float sum = wred(v.x + v.y);
  float sq  = wred(v.x * v.x + v.y * v.y);
  float mean = sum * (1.f / Cn);
  float var  = sq * (1.f / Cn) - mean * mean;
  float rstd = rsqrtf(var + 1e-5f);
  int c0 = lane * 2;
  short2 o;
  o.x = f2bf((v.x - mean) * rstd * g[c0]     + be[c0]);
  o.y = f2bf((v.y - mean) * rstd * g[c0 + 1] + be[c0 + 1]);
  *(short2*)(out + (size_t)row * Cn + c0) = o;
}

// ---------------- generic tall GEMM ----------------
constexpr int LDW = 24;
template<int K, int NTOT, int EPI>
__global__ __launch_bounds__(256) void k_gemm(const short* __restrict__ A,
                                              const short* __restrict__ W,
                                              const float* __restrict__ bias,
                                              const float* __restrict__ aux,
                                              float* __restrict__ outF,
                                              short* __restrict__ outB) {
  __shared__ __attribute__((aligned(16))) short ldsW[64][K + LDW];
  const int t = threadIdx.x;
  const int wave = t >> 6, lane = t & 63;
  const int m_base = blockIdx.x * 64 + wave * 16;
  const int ar = m_base + (lane & 15);
  const int kb = (lane >> 4) * 8;

  bf16x8 af[K / 32];
  #pragma unroll
  for (int s = 0; s < K / 32; ++s)
    af[s] = *(const bf16x8*)(A + (size_t)ar * K + s * 32 + kb);

  for (int nb = 0; nb < NTOT / 64; ++nb) {
    __syncthreads();
    constexpr int LPR = K / 8;
    #pragma unroll
    for (int i = 0; i < 64 * LPR / 256; ++i) {
      int idx = i * 256 + t;
      int n = idx / LPR, kk = (idx % LPR) * 8;
      *(bf16x8*)(&ldsW[n][kk]) = *(const bf16x8*)(W + (size_t)(nb * 64 + n) * K + kk);
    }
    __syncthreads();

    f32x4 acc[4];
    #pragma unroll
    for (int tt = 0; tt < 4; ++tt) acc[tt] = (f32x4){0.f, 0.f, 0.f, 0.f};
    #pragma unroll
    for (int s = 0; s < K / 32; ++s) {
      #pragma unroll
      for (int tt = 0; tt < 4; ++tt) {
        bf16x8 bfr = *(const bf16x8*)(&ldsW[tt * 16 + (lane & 15)][s * 32 + kb]);
        acc[tt] = __builtin_amdgcn_mfma_f32_16x16x32_bf16(af[s], bfr, acc[tt], 0, 0, 0);
      }
    }

    #pragma unroll
    for (int tt = 0; tt < 4; ++tt) {
      #pragma unroll
      for (int r = 0; r < 4; ++r) {
        int m = m_base + (lane >> 4) * 4 + r;
        int col = nb * 64 + tt * 16 + (lane & 15);
        float v = acc[tt][r] + bias[col];
        if (EPI == 0) {
          int win = m / NTOK, tok = m % NTOK;
          int qi = col >> 7, cc = col & 127;
          outB[(((size_t)win * 3 + qi) * NTOK + tok) * Cn + cc] = f2bf(v);
        } else if (EPI == 1) {
          int win = m / NTOK, tok = m % NTOK;
          int b = win >> 6, wi = win & 63;
          int hr = (wi >> 3) * 7 + tok / 7 + SHIFT_; if (hr >= Hn) hr -= Hn;
          int wr = (wi & 7) * 7 + tok % 7 + SHIFT_;  if (wr >= Wn) wr -= Wn;
          size_t dst = (size_t)(b * Ln + hr * Wn + wr) * Cn + col;
          outF[dst] = aux[dst] + v;
        } else if (EPI == 2) {
          float gg = 0.5f * v * (1.f + erff(v * 0.70710678f));
          outB[(size_t)m * NTOT + col] = f2bf(gg);
        } else {
          size_t dst = (size_t)m * Cn + col;
          outF[dst] = outF[dst] + v;
        }
      }
    }
  }
}

// ---------------- MFMA window attention ----------------
// 1 window / block, 1 head / wave. d = 32 == MFMA K.
// S: 4x4 tiles of 16x16; softmax in-register; P -> LDS fragment-interleaved;
// V staged transposed, j-slot XOR-swizzled (3-bit involution: slot = (j>>3)^(c&7))
// so PV B-fragment ds_read_b128 spreads across all 8 bank-quads.
__global__ __launch_bounds__(256, 3) void k_attn(const short* __restrict__ qkv,
                                                 short* __restrict__ out) {
  __shared__ __attribute__((aligned(16))) short sVT[8192];      // 16 KB
  __shared__ __attribute__((aligned(16))) short sP[4][4096];    // 32 KB
  const int t = threadIdx.x;
  const int wave = t >> 6, lane = t & 63;
  const int l15 = lane & 15, g = lane >> 4;
  const int h = wave;
  const int win = blockIdx.x;
  const short* baseQ = qkv + (size_t)win * 3 * NTOK * Cn;
  const short* baseK = baseQ + NTOK * Cn;
  const short* baseV = baseK + NTOK * Cn;

  // ---- stage V transposed into swizzled layout ----
  // VT elem(c,j): idx = (c>>4)*1024 + (c&15)*64 + ((j>>3)^(c&7))*8 + (j&7)
  for (int i = t; i < NTOK * 16; i += 256) {     // 49 rows x 16 chunks of 8
    int j = i >> 4, cb = (i & 15) * 8;
    int jj = j >> 3, u = j & 7;
    bf16x8 v = *(const bf16x8*)(baseV + (size_t)j * Cn + cb);
    #pragma unroll
    for (int uu = 0; uu < 8; ++uu) {
      int c = cb + uu;
      sVT[(c >> 4) * 1024 + (c & 15) * 64 + ((jj ^ (c & 7)) << 3) + u] = v[uu];
    }
  }
  // zero pad j in [49,64)
  for (int i = t; i < 128 * 15; i += 256) {
    int c = i / 15, j = 49 + i % 15;
    sVT[(c >> 4) * 1024 + (c & 15) * 64 + (((j >> 3) ^ (c & 7)) << 3) + (j & 7)] = 0;
  }

  // ---- QK^T via MFMA, fragments straight from global ----
  bf16x8 aq[4], bk[4];
  #pragma unroll
  for (int mi = 0; mi < 4; ++mi)
    aq[mi] = *(const bf16x8*)(baseQ + (size_t)(mi * 16 + l15) * Cn + h * 32 + g * 8);
  #pragma unroll
  for (int ni = 0; ni < 4; ++ni)
    bk[ni] = *(const bf16x8*)(baseK + (size_t)(ni * 16 + l15) * Cn + h * 32 + g * 8);

  f32x4 s[4][4];
  #pragma unroll
  for (int mi = 0; mi < 4; ++mi)
    #pragma unroll
    for (int ni = 0; ni < 4; ++ni) {
      s[mi][ni] = (f32x4){0.f, 0.f, 0.f, 0.f};
      s[mi][ni] = __builtin_amdgcn_mfma_f32_16x16x32_bf16(aq[mi], bk[ni], s[mi][ni], 0, 0, 0);
    }

  // ---- softmax (row's 64 cols live in the 16-lane group sharing g) ----
  const float SC = 0.17677669529663687f;   // 1/sqrt(32)
  #pragma unroll
  for (int mi = 0; mi < 4; ++mi) {
    #pragma unroll
    for (int r = 0; r < 4; ++r) {
      float a0 = s[mi][0][r] * SC, a1 = s[mi][1][r] * SC, a2 = s[mi][2][r] * SC;
      float a3 = (l15 == 0) ? s[mi][3][r] * SC : -1e30f;   // col 48 only valid one
      float m = fmaxf(fmaxf(a0, a1), fmaxf(a2, a3));
      #pragma unroll
      for (int o = 8; o >= 1; o >>= 1) m = fmaxf(m, __shfl_xor(m, o));
      float e0 = __expf(a0 - m), e1 = __expf(a1 - m), e2 = __expf(a2 - m);
      float e3 = (l15 == 0) ? __expf(a3 - m) : 0.f;
      float ss = e0 + e1 + e2 + e3;
      #pragma unroll
      for (int o = 8; o >= 1; o >>= 1) ss += __shfl_xor(ss, o);
      float inv = 1.f / ss;
      int rr = 4 * g + r;
      float ee[4] = {e0, e1, e2, e3};
      #pragma unroll
      for (int ni = 0; ni < 4; ++ni) {
        int col = 16 * ni + l15;
        // P elem(row,col): ((row>>4)*2 + (col>>5))*512 + (row&15)*32 + ((col>>3)&3)*8 + (col&7)
        sP[wave][(mi * 2 + (col >> 5)) * 512 + rr * 32 + (((col >> 3) & 3) * 8) + (col & 7)]
            = f2bf(ee[ni] * inv);
      }
    }
  }

  __syncthreads();   // VT visible to all waves

  // ---- PV via MFMA ----
  f32x4 o_[4][2];
  #pragma unroll
  for (int mi = 0; mi < 4; ++mi)
    #pragma unroll
    for (int ni = 0; ni < 2; ++ni) o_[mi][ni] = (f32x4){0.f, 0.f, 0.f, 0.f};

  #pragma unroll
  for (int ks = 0; ks < 2; ++ks) {
    bf16x8 bv[2];
    #pragma unroll
    for (int ni = 0; ni < 2; ++ni)
      bv[ni] = *(const bf16x8*)(&sVT[(h * 2 + ni) * 1024 + l15 * 64 +
                                     (((ks * 4 + g) ^ (l15 & 7)) << 3)]);
    #pragma unroll
    for (int mi = 0; mi < 4; ++mi) {
      bf16x8 ap = *(const bf16x8*)(&sP[wave][(mi * 2 + ks) * 512 + l15 * 32 + g * 8]);
      #pragma unroll
      for (int ni = 0; ni < 2; ++ni)
        o_[mi][ni] = __builtin_amdgcn_mfma_f32_16x16x32_bf16(ap, bv[ni], o_[mi][ni], 0, 0, 0);
    }
  }

  // ---- store O (bf16, [win*49+i][128]) ----
  #pragma unroll
  for (int mi = 0; mi < 4; ++mi) {
    #pragma unroll
    for (int r = 0; r < 4; ++r) {
      int i = 16 * mi + 4 * g + r;
      if (i < NTOK) {
        short* orow = out + ((size_t)win * NTOK + i) * Cn + h * 32;
        #pragma unroll
        for (int ni = 0; ni < 2; ++ni)
          orow[16 * ni + l15] = f2bf(o_[mi][ni][r]);
      }
    }
  }
}

extern "C" void kernel_launch(void* const* d_in, const int* in_sizes, int n_in,
                              void* d_out, int out_size, void* d_ws, size_t ws_size,
                              hipStream_t stream) {
  const float* x     = (const float*)d_in[0];
  const float* g1    = (const float*)d_in[1];
  const float* be1   = (const float*)d_in[2];
  const float* Wqkv  = (const float*)d_in[3];
  const float* bqkv  = (const float*)d_in[4];
  const float* Wproj = (const float*)d_in[5];
  const float* bproj = (const float*)d_in[6];
  const float* g2    = (const float*)d_in[7];
  const float* be2   = (const float*)d_in[8];
  const float* Wm1   = (const float*)d_in[9];
  const float* bm1   = (const float*)d_in[10];
  const float* Wm2   = (const float*)d_in[11];
  const float* bm2   = (const float*)d_in[12];
  float* out = (float*)d_out;

  char* ws = (char*)d_ws;
  size_t SA = (size_t)Mtot * Cn * 2;
  size_t SB = (size_t)Mtot * HID * 2;
  short* bufA = (short*)ws;
  short* bufB = (short*)(ws + SA);
  short* wq = (short*)(ws + SA + SB);
  short* wp = wq + 384 * 128;
  short* w1 = wp + 128 * 128;
  short* w2 = w1 + 384 * 128;

  k_cvt<<<192, 256, 0, stream>>>(Wqkv, wq, 49152);
  k_cvt<<<64, 256, 0, stream>>>(Wproj, wp, 16384);
  k_cvt<<<192, 256, 0, stream>>>(Wm1, w1, 49152);
  k_cvt<<<192, 256, 0, stream>>>(Wm2, w2, 49152);

  k_ln1<<<Mtot / 4, 256, 0, stream>>>(x, g1, be1, bufA);
  k_gemm<128, 384, 0><<<Mtot / 64, 256, 0, stream>>>(bufA, wq, bqkv, nullptr, nullptr, bufB);
  k_attn<<<NWIN, 256, 0, stream>>>(bufB, bufA);
  k_gemm<128, 128, 1><<<Mtot / 64, 256, 0, stream>>>(bufA, wp, bproj, x, out, nullptr);
  k_ln2<<<Mtot / 4, 256, 0, stream>>>(out, g2, be2, bufA);
  k_gemm<128, 384, 2><<<Mtot / 64, 256, 0, stream>>>(bufA, w1, bm1, nullptr, nullptr, bufB);
  k_gemm<384, 128, 3><<<Mtot / 64, 256, 0, stream>>>(bufB, w2, bm2, nullptr, out, nullptr);
}

// Round 4
// 423.337 us; speedup vs baseline: 1.7556x; 1.0061x over previous
//
#include <hip/hip_runtime.h>
#include <hip/hip_bf16.h>
#include <cstdint>

typedef short bf16x8 __attribute__((ext_vector_type(8)));
typedef float f32x4 __attribute__((ext_vector_type(4)));

constexpr int Bn = 64, Hn = 56, Wn = 56, Cn = 128, Ln = 3136;
constexpr int NWIN = 4096;          // 64 imgs * 8*8 windows
constexpr int NTOK = 49;            // 7*7
constexpr int Mtot = NWIN * NTOK;   // 200704
constexpr int HID = 384;
constexpr int SHIFT_ = 3;

__device__ __forceinline__ float bf2f(short s) {
  union { uint32_t u; float f; } c; c.u = ((uint32_t)(uint16_t)s) << 16; return c.f;
}
__device__ __forceinline__ short f2bf(float f) {
  union { float f; uint32_t u; } c; c.f = f;
  uint32_t r = (c.u + 0x7FFFu + ((c.u >> 16) & 1u)) >> 16;
  return (short)r;
}
__device__ __forceinline__ float wred(float v) {
  #pragma unroll
  for (int o = 32; o > 0; o >>= 1) v += __shfl_xor(v, o);
  return v;
}

// ---------------- all four weight converts in one launch ----------------
__global__ void k_cvt4(const float* __restrict__ s0, const float* __restrict__ s1,
                       const float* __restrict__ s2, const float* __restrict__ s3,
                       short* __restrict__ d0, short* __restrict__ d1,
                       short* __restrict__ d2, short* __restrict__ d3) {
  int i = blockIdx.x * 256 + threadIdx.x;
  if (i < 49152) d0[i] = f2bf(s0[i]);
  else if (i < 65536) d1[i - 49152] = f2bf(s1[i - 49152]);
  else if (i < 114688) d2[i - 65536] = f2bf(s2[i - 65536]);
  else if (i < 163840) d3[i - 114688] = f2bf(s3[i - 114688]);
}

// ---------------- LN1 + roll(-3,-3) + window partition (gather) ----------------
__global__ __launch_bounds__(256) void k_ln1(const float* __restrict__ x,
                                             const float* __restrict__ g,
                                             const float* __restrict__ be,
                                             short* __restrict__ out) {
  int wave = threadIdx.x >> 6, lane = threadIdx.x & 63;
  int row = blockIdx.x * 4 + wave;
  int win = row / NTOK, tok = row % NTOK;
  int b = win >> 6, wi = win & 63;
  int wh = wi >> 3, ww = wi & 7;
  int hr = wh * 7 + tok / 7;
  int wr = ww * 7 + tok % 7;
  int hs = hr + SHIFT_; if (hs >= Hn) hs -= Hn;
  int ws2 = wr + SHIFT_; if (ws2 >= Wn) ws2 -= Wn;
  const float* xr = x + (size_t)(b * Ln + hs * Wn + ws2) * Cn;
  float2 v = *(const float2*)(xr + lane * 2);
  float sum = wred(v.x + v.y);
  float sq  = wred(v.x * v.x + v.y * v.y);
  float mean = sum * (1.f / Cn);
  float var  = sq * (1.f / Cn) - mean * mean;
  float rstd = rsqrtf(var + 1e-5f);
  int c0 = lane * 2;
  short2 o;
  o.x = f2bf((v.x - mean) * rstd * g[c0]     + be[c0]);
  o.y = f2bf((v.y - mean) * rstd * g[c0 + 1] + be[c0 + 1]);
  *(short2*)(out + (size_t)row * Cn + c0) = o;
}

// ---------------- tall GEMM, hoisted epilogues ----------------
// EPI: 0 = qkv scatter (bf16), 2 = tanh-GELU (bf16), 3 = out += v (f32)
template<int K, int NTOT, int EPI>
__global__ __launch_bounds__(256) void k_gemm(const short* __restrict__ A,
                                              const short* __restrict__ W,
                                              const float* __restrict__ bias,
                                              float* __restrict__ outF,
                                              short* __restrict__ outB) {
  __shared__ __attribute__((aligned(16))) short ldsW[64][K + 8];
  const int t = threadIdx.x;
  const int wave = t >> 6, lane = t & 63;
  const int l15 = lane & 15, g = lane >> 4;
  const int m_base = blockIdx.x * 64 + wave * 16;
  const int ar = m_base + l15;
  const int kb = g * 8;

  bf16x8 af[K / 32];
  #pragma unroll
  for (int s = 0; s < K / 32; ++s)
    af[s] = *(const bf16x8*)(A + (size_t)ar * K + s * 32 + kb);

  // hoisted per-r output bases (m-row math done once)
  short* b0[4]; short* b2[4]; float* b3[4];
  #pragma unroll
  for (int r = 0; r < 4; ++r) {
    int m = m_base + 4 * g + r;
    if (EPI == 0) {
      int win = m / NTOK, tok = m - win * NTOK;
      b0[r] = outB + ((size_t)win * 3 * NTOK + tok) * Cn + l15;
    } else if (EPI == 2) {
      b2[r] = outB + (size_t)m * NTOT + l15;
    } else {
      b3[r] = outF + (size_t)m * Cn + l15;
    }
  }

  #pragma unroll
  for (int nb = 0; nb < NTOT / 64; ++nb) {
    __syncthreads();
    constexpr int LPR = K / 8;
    #pragma unroll
    for (int i = 0; i < 64 * LPR / 256; ++i) {
      int idx = i * 256 + t;
      int n = idx / LPR, kk = (idx % LPR) * 8;
      *(bf16x8*)(&ldsW[n][kk]) = *(const bf16x8*)(W + (size_t)(nb * 64 + n) * K + kk);
    }
    __syncthreads();

    f32x4 acc[4];
    #pragma unroll
    for (int tt = 0; tt < 4; ++tt) acc[tt] = (f32x4){0.f, 0.f, 0.f, 0.f};
    #pragma unroll
    for (int s = 0; s < K / 32; ++s) {
      #pragma unroll
      for (int tt = 0; tt < 4; ++tt) {
        bf16x8 bfr = *(const bf16x8*)(&ldsW[tt * 16 + l15][s * 32 + kb]);
        acc[tt] = __builtin_amdgcn_mfma_f32_16x16x32_bf16(af[s], bfr, acc[tt], 0, 0, 0);
      }
    }

    #pragma unroll
    for (int tt = 0; tt < 4; ++tt) {
      const int colc = nb * 64 + tt * 16;          // compile-time after unroll
      float bv = bias[colc + l15];
      #pragma unroll
      for (int r = 0; r < 4; ++r) {
        float v = acc[tt][r] + bv;
        if (EPI == 0) {
          b0[r][(colc >> 7) * (3 * NTOK - NTOK) * 0 + ((colc >> 7) * NTOK * Cn) + (colc & 127)] = f2bf(v);
        } else if (EPI == 2) {
          float u = v + 0.044715f * v * v * v;
          float e = __expf(1.5957691216f * u);     // exp(2*sqrt(2/pi)*u)
          float th = 1.f - 2.f / (e + 1.f);
          b2[r][colc] = f2bf(0.5f * v * (1.f + th));
        } else {
          float* p = b3[r] + colc;
          *p = *p + v;
        }
      }
    }
  }
}

// ---------------- proj GEMM + un-window + roll + residual + fused LN2 ----------------
// A rows are strided: row m lives at Awin + win*3*49*128 + tok*128 (attn wrote O in-place
// into the q-slot of the qkv buffer). Writes h (f32, plain order) and LN2(h) (bf16, plain).
__global__ __launch_bounds__(256) void k_proj(const short* __restrict__ A,
                                              const short* __restrict__ W,
                                              const float* __restrict__ bias,
                                              const float* __restrict__ x,
                                              const float* __restrict__ g2,
                                              const float* __restrict__ be2,
                                              float* __restrict__ hOut,
                                              short* __restrict__ lnOut) {
  __shared__ __attribute__((aligned(16))) short ldsW[128][136];
  const int t = threadIdx.x;
  const int wave = t >> 6, lane = t & 63;
  const int l15 = lane & 15, g = lane >> 4;
  const int m_base = blockIdx.x * 64 + wave * 16;
  const int kb = g * 8;

  // strided A-frag load (attn output in q-slot)
  {
  }
  const int arow = m_base + l15;
  const int awin = arow / NTOK, atok = arow - awin * NTOK;
  const short* abase = A + (size_t)awin * 3 * NTOK * Cn + (size_t)atok * Cn;
  bf16x8 af[4];
  #pragma unroll
  for (int s = 0; s < 4; ++s)
    af[s] = *(const bf16x8*)(abase + s * 32 + kb);

  // stage all of Wproj (128x128)
  #pragma unroll
  for (int i = 0; i < 8; ++i) {
    int idx = i * 256 + t;
    int n = idx >> 4, kk = (idx & 15) * 8;
    *(bf16x8*)(&ldsW[n][kk]) = *(const bf16x8*)(W + (size_t)n * Cn + kk);
  }
  __syncthreads();

  f32x4 acc[8];
  #pragma unroll
  for (int tt = 0; tt < 8; ++tt) acc[tt] = (f32x4){0.f, 0.f, 0.f, 0.f};
  #pragma unroll
  for (int s = 0; s < 4; ++s) {
    #pragma unroll
    for (int tt = 0; tt < 8; ++tt) {
      bf16x8 bfr = *(const bf16x8*)(&ldsW[tt * 16 + l15][s * 32 + kb]);
      acc[tt] = __builtin_amdgcn_mfma_f32_16x16x32_bf16(af[s], bfr, acc[tt], 0, 0, 0);
    }
  }

  // per-r plain-row offsets (un-window + roll(+3,+3))
  size_t off[4];
  #pragma unroll
  for (int r = 0; r < 4; ++r) {
    int m = m_base + 4 * g + r;
    int win = m / NTOK, tok = m - win * NTOK;
    int b = win >> 6, wi = win & 63;
    int hr = (wi >> 3) * 7 + tok / 7 + SHIFT_; if (hr >= Hn) hr -= Hn;
    int wr = (wi & 7) * 7 + tok % 7 + SHIFT_;  if (wr >= Wn) wr -= Wn;
    off[r] = (size_t)(b * Ln + hr * Wn + wr) * Cn + l15;
  }

  #pragma unroll
  for (int r = 0; r < 4; ++r) {
    float hv[8];
    float s1 = 0.f, s2 = 0.f;
    #pragma unroll
    for (int tt = 0; tt < 8; ++tt) {
      hv[tt] = acc[tt][r] + bias[tt * 16 + l15] + x[off[r] + tt * 16];
      s1 += hv[tt];
      s2 += hv[tt] * hv[tt];
    }
    #pragma unroll
    for (int o = 8; o >= 1; o >>= 1) { s1 += __shfl_xor(s1, o); s2 += __shfl_xor(s2, o); }
    float mean = s1 * (1.f / Cn);
    float var  = s2 * (1.f / Cn) - mean * mean;
    float rstd = rsqrtf(var + 1e-5f);
    #pragma unroll
    for (int tt = 0; tt < 8; ++tt) {
      hOut[off[r] + tt * 16] = hv[tt];
      int c = tt * 16 + l15;
      lnOut[off[r] + tt * 16] = f2bf((hv[tt] - mean) * rstd * g2[c] + be2[c]);
    }
  }
}

// ---------------- MFMA window attention (O written in-place to q-slot) ----------------
__global__ __launch_bounds__(256, 3) void k_attn(const short* __restrict__ qkv,
                                                 short* __restrict__ out) {
  __shared__ __attribute__((aligned(16))) short sVT[8192];      // 16 KB
  __shared__ __attribute__((aligned(16))) short sP[4][4096];    // 32 KB
  const int t = threadIdx.x;
  const int wave = t >> 6, lane = t & 63;
  const int l15 = lane & 15, g = lane >> 4;
  const int h = wave;
  const int win = blockIdx.x;
  const short* baseQ = qkv + (size_t)win * 3 * NTOK * Cn;
  const short* baseK = baseQ + NTOK * Cn;
  const short* baseV = baseK + NTOK * Cn;

  // ---- stage V transposed into swizzled layout ----
  // VT elem(c,j): idx = (c>>4)*1024 + (c&15)*64 + ((j>>3)^(c&7))*8 + (j&7)
  for (int i = t; i < NTOK * 16; i += 256) {
    int j = i >> 4, cb = (i & 15) * 8;
    int jj = j >> 3, u = j & 7;
    bf16x8 v = *(const bf16x8*)(baseV + (size_t)j * Cn + cb);
    #pragma unroll
    for (int uu = 0; uu < 8; ++uu) {
      int c = cb + uu;
      sVT[(c >> 4) * 1024 + (c & 15) * 64 + ((jj ^ (c & 7)) << 3) + u] = v[uu];
    }
  }
  for (int i = t; i < 128 * 15; i += 256) {
    int c = i / 15, j = 49 + i % 15;
    sVT[(c >> 4) * 1024 + (c & 15) * 64 + (((j >> 3) ^ (c & 7)) << 3) + (j & 7)] = 0;
  }

  // ---- QK^T via MFMA, fragments straight from global ----
  bf16x8 aq[4], bk[4];
  #pragma unroll
  for (int mi = 0; mi < 4; ++mi)
    aq[mi] = *(const bf16x8*)(baseQ + (size_t)(mi * 16 + l15) * Cn + h * 32 + g * 8);
  #pragma unroll
  for (int ni = 0; ni < 4; ++ni)
    bk[ni] = *(const bf16x8*)(baseK + (size_t)(ni * 16 + l15) * Cn + h * 32 + g * 8);

  f32x4 s[4][4];
  #pragma unroll
  for (int mi = 0; mi < 4; ++mi)
    #pragma unroll
    for (int ni = 0; ni < 4; ++ni) {
      s[mi][ni] = (f32x4){0.f, 0.f, 0.f, 0.f};
      s[mi][ni] = __builtin_amdgcn_mfma_f32_16x16x32_bf16(aq[mi], bk[ni], s[mi][ni], 0, 0, 0);
    }

  // ---- softmax (row's 64 cols live in the 16-lane group sharing g) ----
  const float SC = 0.17677669529663687f;   // 1/sqrt(32)
  #pragma unroll
  for (int mi = 0; mi < 4; ++mi) {
    #pragma unroll
    for (int r = 0; r < 4; ++r) {
      float a0 = s[mi][0][r] * SC, a1 = s[mi][1][r] * SC, a2 = s[mi][2][r] * SC;
      float a3 = (l15 == 0) ? s[mi][3][r] * SC : -1e30f;   // col 48 only valid one
      float m = fmaxf(fmaxf(a0, a1), fmaxf(a2, a3));
      #pragma unroll
      for (int o = 8; o >= 1; o >>= 1) m = fmaxf(m, __shfl_xor(m, o));
      float e0 = __expf(a0 - m), e1 = __expf(a1 - m), e2 = __expf(a2 - m);
      float e3 = (l15 == 0) ? __expf(a3 - m) : 0.f;
      float ss = e0 + e1 + e2 + e3;
      #pragma unroll
      for (int o = 8; o >= 1; o >>= 1) ss += __shfl_xor(ss, o);
      float inv = 1.f / ss;
      int rr = 4 * g + r;
      float ee[4] = {e0, e1, e2, e3};
      #pragma unroll
      for (int ni = 0; ni < 4; ++ni) {
        int col = 16 * ni + l15;
        sP[wave][(mi * 2 + (col >> 5)) * 512 + rr * 32 + (((col >> 3) & 3) * 8) + (col & 7)]
            = f2bf(ee[ni] * inv);
      }
    }
  }

  __syncthreads();   // VT visible; also drains all global reads before in-place store

  // ---- PV via MFMA ----
  f32x4 o_[4][2];
  #pragma unroll
  for (int mi = 0; mi < 4; ++mi)
    #pragma unroll
    for (int ni = 0; ni < 2; ++ni) o_[mi][ni] = (f32x4){0.f, 0.f, 0.f, 0.f};

  #pragma unroll
  for (int ks = 0; ks < 2; ++ks) {
    bf16x8 bv[2];
    #pragma unroll
    for (int ni = 0; ni < 2; ++ni)
      bv[ni] = *(const bf16x8*)(&sVT[(h * 2 + ni) * 1024 + l15 * 64 +
                                     (((ks * 4 + g) ^ (l15 & 7)) << 3)]);
    #pragma unroll
    for (int mi = 0; mi < 4; ++mi) {
      bf16x8 ap = *(const bf16x8*)(&sP[wave][(mi * 2 + ks) * 512 + l15 * 32 + g * 8]);
      #pragma unroll
      for (int ni = 0; ni < 2; ++ni)
        o_[mi][ni] = __builtin_amdgcn_mfma_f32_16x16x32_bf16(ap, bv[ni], o_[mi][ni], 0, 0, 0);
    }
  }

  // ---- store O into the q-slot of this window (in-place) ----
  #pragma unroll
  for (int mi = 0; mi < 4; ++mi) {
    #pragma unroll
    for (int r = 0; r < 4; ++r) {
      int i = 16 * mi + 4 * g + r;
      if (i < NTOK) {
        short* orow = out + ((size_t)win * 3 * NTOK + i) * Cn + h * 32;
        #pragma unroll
        for (int ni = 0; ni < 2; ++ni)
          orow[16 * ni + l15] = f2bf(o_[mi][ni][r]);
      }
    }
  }
}

extern "C" void kernel_launch(void* const* d_in, const int* in_sizes, int n_in,
                              void* d_out, int out_size, void* d_ws, size_t ws_size,
                              hipStream_t stream) {
  const float* x     = (const float*)d_in[0];
  const float* g1    = (const float*)d_in[1];
  const float* be1   = (const float*)d_in[2];
  const float* Wqkv  = (const float*)d_in[3];
  const float* bqkv  = (const float*)d_in[4];
  const float* Wproj = (const float*)d_in[5];
  const float* bproj = (const float*)d_in[6];
  const float* g2    = (const float*)d_in[7];
  const float* be2   = (const float*)d_in[8];
  const float* Wm1   = (const float*)d_in[9];
  const float* bm1   = (const float*)d_in[10];
  const float* Wm2   = (const float*)d_in[11];
  const float* bm2   = (const float*)d_in[12];
  float* out = (float*)d_out;

  char* ws = (char*)d_ws;
  size_t SA = (size_t)Mtot * Cn * 2;    // 51.4 MB
  size_t SB = (size_t)Mtot * HID * 2;   // 154.1 MB
  short* bufA = (short*)ws;
  short* bufB = (short*)(ws + SA);
  short* wq = (short*)(ws + SA + SB);
  short* wp = wq + 384 * 128;
  short* w1 = wp + 128 * 128;
  short* w2 = w1 + 384 * 128;

  k_cvt4<<<640, 256, 0, stream>>>(Wqkv, Wproj, Wm1, Wm2, wq, wp, w1, w2);

  k_ln1<<<Mtot / 4, 256, 0, stream>>>(x, g1, be1, bufA);
  k_gemm<128, 384, 0><<<Mtot / 64, 256, 0, stream>>>(bufA, wq, bqkv, nullptr, bufB);
  k_attn<<<NWIN, 256, 0, stream>>>(bufB, bufB);
  k_proj<<<Mtot / 64, 256, 0, stream>>>(bufB, wp, bproj, x, g2, be2, out, bufA);
  k_gemm<128, 384, 2><<<Mtot / 64, 256, 0, stream>>>(bufA, w1, bm1, nullptr, bufB);
  k_gemm<384, 128, 3><<<Mtot / 64, 256, 0, stream>>>(bufB, w2, bm2, out, nullptr);
}

// Round 6
// 415.675 us; speedup vs baseline: 1.7880x; 1.0184x over previous
//
#include <hip/hip_runtime.h>
#include <hip/hip_bf16.h>
#include <cstdint>

typedef short bf16x8 __attribute__((ext_vector_type(8)));
typedef float f32x4 __attribute__((ext_vector_type(4)));

constexpr int Bn = 64, Hn = 56, Wn = 56, Cn = 128, Ln = 3136;
constexpr int NWIN = 4096;          // 64 imgs * 8*8 windows
constexpr int NTOK = 49;            // 7*7
constexpr int Mtot = NWIN * NTOK;   // 200704
constexpr int HID = 384;
constexpr int SHIFT_ = 3;

__device__ __forceinline__ float bf2f(short s) {
  union { uint32_t u; float f; } c; c.u = ((uint32_t)(uint16_t)s) << 16; return c.f;
}
__device__ __forceinline__ short f2bf(float f) {
  union { float f; uint32_t u; } c; c.f = f;
  uint32_t r = (c.u + 0x7FFFu + ((c.u >> 16) & 1u)) >> 16;
  return (short)r;
}
__device__ __forceinline__ float wred(float v) {
  #pragma unroll
  for (int o = 32; o > 0; o >>= 1) v += __shfl_xor(v, o);
  return v;
}

// plain-order offset of window-order row m (un-window + roll(+3,+3)), + lane col
__device__ __forceinline__ size_t plain_off(int m, int l15) {
  int win = m / NTOK, tok = m - win * NTOK;
  int b = win >> 6, wi = win & 63;
  int hr = (wi >> 3) * 7 + tok / 7 + SHIFT_; if (hr >= Hn) hr -= Hn;
  int wr = (wi & 7) * 7 + tok % 7 + SHIFT_;  if (wr >= Wn) wr -= Wn;
  return (size_t)(b * Ln + hr * Wn + wr) * Cn + l15;
}

// ---------------- all four weight converts in one launch ----------------
__global__ void k_cvt4(const float* __restrict__ s0, const float* __restrict__ s1,
                       const float* __restrict__ s2, const float* __restrict__ s3,
                       short* __restrict__ d0, short* __restrict__ d1,
                       short* __restrict__ d2, short* __restrict__ d3) {
  int i = blockIdx.x * 256 + threadIdx.x;
  if (i < 49152) d0[i] = f2bf(s0[i]);
  else if (i < 65536) d1[i - 49152] = f2bf(s1[i - 49152]);
  else if (i < 114688) d2[i - 65536] = f2bf(s2[i - 65536]);
  else if (i < 163840) d3[i - 114688] = f2bf(s3[i - 114688]);
}

// ---------------- LN1 + roll(-3,-3) + window partition (gather) ----------------
__global__ __launch_bounds__(256) void k_ln1(const float* __restrict__ x,
                                             const float* __restrict__ g,
                                             const float* __restrict__ be,
                                             short* __restrict__ out) {
  int wave = threadIdx.x >> 6, lane = threadIdx.x & 63;
  int row = blockIdx.x * 4 + wave;
  int win = row / NTOK, tok = row % NTOK;
  int b = win >> 6, wi = win & 63;
  int wh = wi >> 3, ww = wi & 7;
  int hr = wh * 7 + tok / 7;
  int wr = ww * 7 + tok % 7;
  int hs = hr + SHIFT_; if (hs >= Hn) hs -= Hn;
  int ws2 = wr + SHIFT_; if (ws2 >= Wn) ws2 -= Wn;
  const float* xr = x + (size_t)(b * Ln + hs * Wn + ws2) * Cn;
  float2 v = *(const float2*)(xr + lane * 2);
  float sum = wred(v.x + v.y);
  float sq  = wred(v.x * v.x + v.y * v.y);
  float mean = sum * (1.f / Cn);
  float var  = sq * (1.f / Cn) - mean * mean;
  float rstd = rsqrtf(var + 1e-5f);
  int c0 = lane * 2;
  short2 o;
  o.x = f2bf((v.x - mean) * rstd * g[c0]     + be[c0]);
  o.y = f2bf((v.y - mean) * rstd * g[c0 + 1] + be[c0 + 1]);
  *(short2*)(out + (size_t)row * Cn + c0) = o;
}

// ---------------- tall GEMM, hoisted epilogues ----------------
// EPI: 0 = qkv scatter (bf16), 2 = tanh-GELU (bf16), 3 = out[m*Cn] = h + v (f32)
template<int K, int NTOT, int EPI>
__global__ __launch_bounds__(256) void k_gemm(const short* __restrict__ A,
                                              const short* __restrict__ W,
                                              const float* __restrict__ bias,
                                              float* __restrict__ outF,
                                              short* __restrict__ outB) {
  __shared__ __attribute__((aligned(16))) short ldsW[64][K + 8];
  const int t = threadIdx.x;
  const int wave = t >> 6, lane = t & 63;
  const int l15 = lane & 15, g = lane >> 4;
  const int m_base = blockIdx.x * 64 + wave * 16;
  const int ar = m_base + l15;
  const int kb = g * 8;

  bf16x8 af[K / 32];
  #pragma unroll
  for (int s = 0; s < K / 32; ++s)
    af[s] = *(const bf16x8*)(A + (size_t)ar * K + s * 32 + kb);

  // hoisted per-r output bases (m-row math done once); EPI3 prefetches h
  short* b0[4]; short* b2[4]; float* b3[4];
  constexpr int NC = (EPI == 3) ? NTOT / 16 : 1;
  float ov[4][NC];
  #pragma unroll
  for (int r = 0; r < 4; ++r) {
    int m = m_base + 4 * g + r;
    if (EPI == 0) {
      int win = m / NTOK, tok = m - win * NTOK;
      b0[r] = outB + ((size_t)win * 3 * NTOK + tok) * Cn + l15;
    } else if (EPI == 2) {
      b2[r] = outB + (size_t)m * NTOT + l15;
    } else {
      b3[r] = outF + (size_t)m * Cn + l15;
      #pragma unroll
      for (int c = 0; c < NC; ++c) ov[r][c] = b3[r][c * 16];   // prefetch h (same cells this thread writes)
    }
  }

  #pragma unroll
  for (int nb = 0; nb < NTOT / 64; ++nb) {
    __syncthreads();
    constexpr int LPR = K / 8;
    #pragma unroll
    for (int i = 0; i < 64 * LPR / 256; ++i) {
      int idx = i * 256 + t;
      int n = idx / LPR, kk = (idx % LPR) * 8;
      *(bf16x8*)(&ldsW[n][kk]) = *(const bf16x8*)(W + (size_t)(nb * 64 + n) * K + kk);
    }
    __syncthreads();

    f32x4 acc[4];
    #pragma unroll
    for (int tt = 0; tt < 4; ++tt) acc[tt] = (f32x4){0.f, 0.f, 0.f, 0.f};
    #pragma unroll
    for (int s = 0; s < K / 32; ++s) {
      #pragma unroll
      for (int tt = 0; tt < 4; ++tt) {
        bf16x8 bfr = *(const bf16x8*)(&ldsW[tt * 16 + l15][s * 32 + kb]);
        acc[tt] = __builtin_amdgcn_mfma_f32_16x16x32_bf16(af[s], bfr, acc[tt], 0, 0, 0);
      }
    }

    #pragma unroll
    for (int tt = 0; tt < 4; ++tt) {
      const int colc = nb * 64 + tt * 16;          // compile-time after unroll
      float bv = bias[colc + l15];
      #pragma unroll
      for (int r = 0; r < 4; ++r) {
        float v = acc[tt][r] + bv;
        if (EPI == 0) {
          b0[r][((colc >> 7) * NTOK * Cn) + (colc & 127)] = f2bf(v);
        } else if (EPI == 2) {
          float u = v + 0.044715f * v * v * v;
          float e = __expf(1.5957691216f * u);     // exp(2*sqrt(2/pi)*u)
          float th = 1.f - 2.f / (e + 1.f);
          b2[r][colc] = f2bf(0.5f * v * (1.f + th));
        } else {
          b3[r][colc] = ov[r][colc >> 4] + v;      // out = h + m
        }
      }
    }
  }
}

// ---------------- proj GEMM + un-window + roll + residual + fused LN2 ----------------
// A rows strided (attn O in q-slot of qkv buffer). Writes h (f32, plain order) and
// LN2(h) (bf16, plain order) — round-4-proven dataflow, ILP-restructured.
__global__ __launch_bounds__(256) void k_proj(const short* __restrict__ A,
                                              const short* __restrict__ W,
                                              const float* __restrict__ bias,
                                              const float* __restrict__ x,
                                              const float* __restrict__ g2,
                                              const float* __restrict__ be2,
                                              float* __restrict__ hOut,
                                              short* __restrict__ lnOut) {
  __shared__ __attribute__((aligned(16))) short ldsW[128 * 128];   // 32 KB, XOR-swizzled
  const int t = threadIdx.x;
  const int wave = t >> 6, lane = t & 63;
  const int l15 = lane & 15, g = lane >> 4;
  const int m_base = blockIdx.x * 64 + wave * 16;
  const int kb = g * 8;

  // per-r plain offsets + prefetch ALL x residual values (overlaps staging/MFMA)
  size_t off[4];
  float xv[4][8];
  #pragma unroll
  for (int r = 0; r < 4; ++r) {
    int m = m_base + 4 * g + r;
    off[r] = plain_off(m, l15);
    #pragma unroll
    for (int c = 0; c < 8; ++c) xv[r][c] = x[off[r] + c * 16];
  }

  // hoisted per-lane bias / LN params (cols c*16 + l15)
  float bv[8], gv[8], bev[8];
  #pragma unroll
  for (int c = 0; c < 8; ++c) {
    bv[c] = bias[c * 16 + l15]; gv[c] = g2[c * 16 + l15]; bev[c] = be2[c * 16 + l15];
  }

  // strided A-frag load (attn output in q-slot)
  const int arow = m_base + l15;
  const int awin = arow / NTOK, atok = arow - awin * NTOK;
  const short* abase = A + (size_t)awin * 3 * NTOK * Cn + (size_t)atok * Cn;
  bf16x8 af[4];
  #pragma unroll
  for (int s = 0; s < 4; ++s)
    af[s] = *(const bf16x8*)(abase + s * 32 + kb);

  // stage Wproj 128x128 with 16B-granule XOR swizzle: granule ^= (row & 7)
  #pragma unroll
  for (int i = 0; i < 8; ++i) {
    int idx = i * 256 + t;
    int n = idx >> 4, gr = idx & 15;
    *(bf16x8*)(&ldsW[n * 128 + ((gr ^ (n & 7)) << 3)]) =
        *(const bf16x8*)(W + (size_t)n * Cn + gr * 8);
  }
  __syncthreads();

  f32x4 acc[8];
  #pragma unroll
  for (int tt = 0; tt < 8; ++tt) acc[tt] = (f32x4){0.f, 0.f, 0.f, 0.f};
  #pragma unroll
  for (int s = 0; s < 4; ++s) {
    #pragma unroll
    for (int tt = 0; tt < 8; ++tt) {
      int row = tt * 16 + l15;
      bf16x8 bfr = *(const bf16x8*)(&ldsW[row * 128 + (((s * 4 + g) ^ (l15 & 7)) << 3)]);
      acc[tt] = __builtin_amdgcn_mfma_f32_16x16x32_bf16(af[s], bfr, acc[tt], 0, 0, 0);
    }
  }

  #pragma unroll
  for (int r = 0; r < 4; ++r) {
    float hv[8];
    float s1 = 0.f, s2 = 0.f;
    #pragma unroll
    for (int tt = 0; tt < 8; ++tt) {
      hv[tt] = acc[tt][r] + bv[tt] + xv[r][tt];
      s1 += hv[tt];
      s2 += hv[tt] * hv[tt];
    }
    #pragma unroll
    for (int o = 8; o >= 1; o >>= 1) { s1 += __shfl_xor(s1, o); s2 += __shfl_xor(s2, o); }
    float mean = s1 * (1.f / Cn);
    float var  = s2 * (1.f / Cn) - mean * mean;
    float rstd = rsqrtf(var + 1e-5f);
    #pragma unroll
    for (int tt = 0; tt < 8; ++tt) {
      hOut[off[r] + tt * 16] = hv[tt];                                           // f32, plain
      lnOut[off[r] + tt * 16] = f2bf((hv[tt] - mean) * rstd * gv[tt] + bev[tt]); // bf16, plain
    }
  }
}

// ---------------- MFMA window attention (O written in-place to q-slot) ----------------
__global__ __launch_bounds__(256, 3) void k_attn(const short* __restrict__ qkv,
                                                 short* __restrict__ out) {
  __shared__ __attribute__((aligned(16))) short sVT[8192];      // 16 KB
  __shared__ __attribute__((aligned(16))) short sP[4][4096];    // 32 KB
  const int t = threadIdx.x;
  const int wave = t >> 6, lane = t & 63;
  const int l15 = lane & 15, g = lane >> 4;
  const int h = wave;
  const int win = blockIdx.x;
  const short* baseQ = qkv + (size_t)win * 3 * NTOK * Cn;
  const short* baseK = baseQ + NTOK * Cn;
  const short* baseV = baseK + NTOK * Cn;

  // ---- stage V transposed into swizzled layout ----
  for (int i = t; i < NTOK * 16; i += 256) {
    int j = i >> 4, cb = (i & 15) * 8;
    int jj = j >> 3, u = j & 7;
    bf16x8 v = *(const bf16x8*)(baseV + (size_t)j * Cn + cb);
    #pragma unroll
    for (int uu = 0; uu < 8; ++uu) {
      int c = cb + uu;
      sVT[(c >> 4) * 1024 + (c & 15) * 64 + ((jj ^ (c & 7)) << 3) + u] = v[uu];
    }
  }
  for (int i = t; i < 128 * 15; i += 256) {
    int c = i / 15, j = 49 + i % 15;
    sVT[(c >> 4) * 1024 + (c & 15) * 64 + (((j >> 3) ^ (c & 7)) << 3) + (j & 7)] = 0;
  }

  // ---- QK^T via MFMA, fragments straight from global ----
  bf16x8 aq[4], bk[4];
  #pragma unroll
  for (int mi = 0; mi < 4; ++mi)
    aq[mi] = *(const bf16x8*)(baseQ + (size_t)(mi * 16 + l15) * Cn + h * 32 + g * 8);
  #pragma unroll
  for (int ni = 0; ni < 4; ++ni)
    bk[ni] = *(const bf16x8*)(baseK + (size_t)(ni * 16 + l15) * Cn + h * 32 + g * 8);

  f32x4 s[4][4];
  #pragma unroll
  for (int mi = 0; mi < 4; ++mi)
    #pragma unroll
    for (int ni = 0; ni < 4; ++ni) {
      s[mi][ni] = (f32x4){0.f, 0.f, 0.f, 0.f};
      s[mi][ni] = __builtin_amdgcn_mfma_f32_16x16x32_bf16(aq[mi], bk[ni], s[mi][ni], 0, 0, 0);
    }

  // ---- softmax (row's 64 cols live in the 16-lane group sharing g) ----
  const float SC = 0.17677669529663687f;   // 1/sqrt(32)
  #pragma unroll
  for (int mi = 0; mi < 4; ++mi) {
    #pragma unroll
    for (int r = 0; r < 4; ++r) {
      float a0 = s[mi][0][r] * SC, a1 = s[mi][1][r] * SC, a2 = s[mi][2][r] * SC;
      float a3 = (l15 == 0) ? s[mi][3][r] * SC : -1e30f;   // col 48 only valid one
      float m = fmaxf(fmaxf(a0, a1), fmaxf(a2, a3));
      #pragma unroll
      for (int o = 8; o >= 1; o >>= 1) m = fmaxf(m, __shfl_xor(m, o));
      float e0 = __expf(a0 - m), e1 = __expf(a1 - m), e2 = __expf(a2 - m);
      float e3 = (l15 == 0) ? __expf(a3 - m) : 0.f;
      float ss = e0 + e1 + e2 + e3;
      #pragma unroll
      for (int o = 8; o >= 1; o >>= 1) ss += __shfl_xor(ss, o);
      float inv = 1.f / ss;
      int rr = 4 * g + r;
      float ee[4] = {e0, e1, e2, e3};
      #pragma unroll
      for (int ni = 0; ni < 4; ++ni) {
        int col = 16 * ni + l15;
        sP[wave][(mi * 2 + (col >> 5)) * 512 + rr * 32 + (((col >> 3) & 3) * 8) + (col & 7)]
            = f2bf(ee[ni] * inv);
      }
    }
  }

  __syncthreads();   // VT visible; also drains global reads before in-place store

  // ---- PV via MFMA ----
  f32x4 o_[4][2];
  #pragma unroll
  for (int mi = 0; mi < 4; ++mi)
    #pragma unroll
    for (int ni = 0; ni < 2; ++ni) o_[mi][ni] = (f32x4){0.f, 0.f, 0.f, 0.f};

  #pragma unroll
  for (int ks = 0; ks < 2; ++ks) {
    bf16x8 bv[2];
    #pragma unroll
    for (int ni = 0; ni < 2; ++ni)
      bv[ni] = *(const bf16x8*)(&sVT[(h * 2 + ni) * 1024 + l15 * 64 +
                                     (((ks * 4 + g) ^ (l15 & 7)) << 3)]);
    #pragma unroll
    for (int mi = 0; mi < 4; ++mi) {
      bf16x8 ap = *(const bf16x8*)(&sP[wave][(mi * 2 + ks) * 512 + l15 * 32 + g * 8]);
      #pragma unroll
      for (int ni = 0; ni < 2; ++ni)
        o_[mi][ni] = __builtin_amdgcn_mfma_f32_16x16x32_bf16(ap, bv[ni], o_[mi][ni], 0, 0, 0);
    }
  }

  // ---- store O into the q-slot of this window (in-place) ----
  #pragma unroll
  for (int mi = 0; mi < 4; ++mi) {
    #pragma unroll
    for (int r = 0; r < 4; ++r) {
      int i = 16 * mi + 4 * g + r;
      if (i < NTOK) {
        short* orow = out + ((size_t)win * 3 * NTOK + i) * Cn + h * 32;
        #pragma unroll
        for (int ni = 0; ni < 2; ++ni)
          orow[16 * ni + l15] = f2bf(o_[mi][ni][r]);
      }
    }
  }
}

extern "C" void kernel_launch(void* const* d_in, const int* in_sizes, int n_in,
                              void* d_out, int out_size, void* d_ws, size_t ws_size,
                              hipStream_t stream) {
  const float* x     = (const float*)d_in[0];
  const float* g1    = (const float*)d_in[1];
  const float* be1   = (const float*)d_in[2];
  const float* Wqkv  = (const float*)d_in[3];
  const float* bqkv  = (const float*)d_in[4];
  const float* Wproj = (const float*)d_in[5];
  const float* bproj = (const float*)d_in[6];
  const float* g2    = (const float*)d_in[7];
  const float* be2   = (const float*)d_in[8];
  const float* Wm1   = (const float*)d_in[9];
  const float* bm1   = (const float*)d_in[10];
  const float* Wm2   = (const float*)d_in[11];
  const float* bm2   = (const float*)d_in[12];
  float* out = (float*)d_out;

  char* ws = (char*)d_ws;
  size_t SA = (size_t)Mtot * Cn * 2;    // 51.4 MB: ln1win / ln2 (plain)
  size_t SB = (size_t)Mtot * HID * 2;   // 154.1 MB: qkv / m1act
  short* bufA = (short*)ws;
  short* bufB = (short*)(ws + SA);
  short* wq = (short*)(ws + SA + SB);
  short* wp = wq + 384 * 128;
  short* w1 = wp + 128 * 128;
  short* w2 = w1 + 384 * 128;

  k_cvt4<<<640, 256, 0, stream>>>(Wqkv, Wproj, Wm1, Wm2, wq, wp, w1, w2);

  k_ln1<<<Mtot / 4, 256, 0, stream>>>(x, g1, be1, bufA);
  k_gemm<128, 384, 0><<<Mtot / 64, 256, 0, stream>>>(bufA, wq, bqkv, nullptr, bufB);
  k_attn<<<NWIN, 256, 0, stream>>>(bufB, bufB);
  k_proj<<<Mtot / 64, 256, 0, stream>>>(bufB, wp, bproj, x, g2, be2, out, bufA);
  k_gemm<128, 384, 2><<<Mtot / 64, 256, 0, stream>>>(bufA, w1, bm1, nullptr, bufB);
  k_gemm<384, 128, 3><<<Mtot / 64, 256, 0, stream>>>(bufB, w2, bm2, out, nullptr);
}

// Round 7
// 399.199 us; speedup vs baseline: 1.8618x; 1.0413x over previous
//
#include <hip/hip_runtime.h>
#include <hip/hip_bf16.h>
#include <cstdint>

typedef short bf16x8 __attribute__((ext_vector_type(8)));
typedef float f32x4 __attribute__((ext_vector_type(4)));

constexpr int Bn = 64, Hn = 56, Wn = 56, Cn = 128, Ln = 3136;
constexpr int NWIN = 4096;          // 64 imgs * 8*8 windows
constexpr int NTOK = 49;            // 7*7
constexpr int Mtot = NWIN * NTOK;   // 200704
constexpr int HID = 384;
constexpr int SHIFT_ = 3;

__device__ __forceinline__ float bf2f(short s) {
  union { uint32_t u; float f; } c; c.u = ((uint32_t)(uint16_t)s) << 16; return c.f;
}
__device__ __forceinline__ short f2bf(float f) {
  union { float f; uint32_t u; } c; c.f = f;
  uint32_t r = (c.u + 0x7FFFu + ((c.u >> 16) & 1u)) >> 16;
  return (short)r;
}
__device__ __forceinline__ float wred(float v) {
  #pragma unroll
  for (int o = 32; o > 0; o >>= 1) v += __shfl_xor(v, o);
  return v;
}

// plain-order offset of window-order row m (un-window + roll(+3,+3)), + lane col
__device__ __forceinline__ size_t plain_off(int m, int l15) {
  int win = m / NTOK, tok = m - win * NTOK;
  int b = win >> 6, wi = win & 63;
  int hr = (wi >> 3) * 7 + tok / 7 + SHIFT_; if (hr >= Hn) hr -= Hn;
  int wr = (wi & 7) * 7 + tok % 7 + SHIFT_;  if (wr >= Wn) wr -= Wn;
  return (size_t)(b * Ln + hr * Wn + wr) * Cn + l15;
}

// ---------------- all four weight converts in one launch ----------------
__global__ void k_cvt4(const float* __restrict__ s0, const float* __restrict__ s1,
                       const float* __restrict__ s2, const float* __restrict__ s3,
                       short* __restrict__ d0, short* __restrict__ d1,
                       short* __restrict__ d2, short* __restrict__ d3) {
  int i = blockIdx.x * 256 + threadIdx.x;
  if (i < 49152) d0[i] = f2bf(s0[i]);
  else if (i < 65536) d1[i - 49152] = f2bf(s1[i - 49152]);
  else if (i < 114688) d2[i - 65536] = f2bf(s2[i - 65536]);
  else if (i < 163840) d3[i - 114688] = f2bf(s3[i - 114688]);
}

// ---------------- LN1 + roll(-3,-3) + window partition (gather) ----------------
__global__ __launch_bounds__(256) void k_ln1(const float* __restrict__ x,
                                             const float* __restrict__ g,
                                             const float* __restrict__ be,
                                             short* __restrict__ out) {
  int wave = threadIdx.x >> 6, lane = threadIdx.x & 63;
  int row = blockIdx.x * 4 + wave;
  int win = row / NTOK, tok = row % NTOK;
  int b = win >> 6, wi = win & 63;
  int wh = wi >> 3, ww = wi & 7;
  int hr = wh * 7 + tok / 7;
  int wr = ww * 7 + tok % 7;
  int hs = hr + SHIFT_; if (hs >= Hn) hs -= Hn;
  int ws2 = wr + SHIFT_; if (ws2 >= Wn) ws2 -= Wn;
  const float* xr = x + (size_t)(b * Ln + hs * Wn + ws2) * Cn;
  float2 v = *(const float2*)(xr + lane * 2);
  float sum = wred(v.x + v.y);
  float sq  = wred(v.x * v.x + v.y * v.y);
  float mean = sum * (1.f / Cn);
  float var  = sq * (1.f / Cn) - mean * mean;
  float rstd = rsqrtf(var + 1e-5f);
  int c0 = lane * 2;
  short2 o;
  o.x = f2bf((v.x - mean) * rstd * g[c0]     + be[c0]);
  o.y = f2bf((v.y - mean) * rstd * g[c0 + 1] + be[c0 + 1]);
  *(short2*)(out + (size_t)row * Cn + c0) = o;
}

// ---------------- QKV GEMM (round-6-proven k_gemm EPI0 path) ----------------
__global__ __launch_bounds__(256) void k_qkvg(const short* __restrict__ A,
                                              const short* __restrict__ W,
                                              const float* __restrict__ bias,
                                              short* __restrict__ outB) {
  __shared__ __attribute__((aligned(16))) short ldsW[64][136];
  const int t = threadIdx.x;
  const int wave = t >> 6, lane = t & 63;
  const int l15 = lane & 15, g = lane >> 4;
  const int m_base = blockIdx.x * 64 + wave * 16;
  const int ar = m_base + l15;
  const int kb = g * 8;

  bf16x8 af[4];
  #pragma unroll
  for (int s = 0; s < 4; ++s)
    af[s] = *(const bf16x8*)(A + (size_t)ar * 128 + s * 32 + kb);

  short* b0[4];
  #pragma unroll
  for (int r = 0; r < 4; ++r) {
    int m = m_base + 4 * g + r;
    int win = m / NTOK, tok = m - win * NTOK;
    b0[r] = outB + ((size_t)win * 3 * NTOK + tok) * Cn + l15;
  }

  #pragma unroll
  for (int nb = 0; nb < 6; ++nb) {
    __syncthreads();
    #pragma unroll
    for (int i = 0; i < 4; ++i) {
      int idx = i * 256 + t;
      int n = idx >> 4, kk = (idx & 15) * 8;
      *(bf16x8*)(&ldsW[n][kk]) = *(const bf16x8*)(W + (size_t)(nb * 64 + n) * 128 + kk);
    }
    __syncthreads();

    f32x4 acc[4];
    #pragma unroll
    for (int tt = 0; tt < 4; ++tt) acc[tt] = (f32x4){0.f, 0.f, 0.f, 0.f};
    #pragma unroll
    for (int s = 0; s < 4; ++s) {
      #pragma unroll
      for (int tt = 0; tt < 4; ++tt) {
        bf16x8 bfr = *(const bf16x8*)(&ldsW[tt * 16 + l15][s * 32 + kb]);
        acc[tt] = __builtin_amdgcn_mfma_f32_16x16x32_bf16(af[s], bfr, acc[tt], 0, 0, 0);
      }
    }

    #pragma unroll
    for (int tt = 0; tt < 4; ++tt) {
      const int colc = nb * 64 + tt * 16;
      float bv = bias[colc + l15];
      #pragma unroll
      for (int r = 0; r < 4; ++r) {
        float v = acc[tt][r] + bv;
        b0[r][((colc >> 7) * NTOK * Cn) + (colc & 127)] = f2bf(v);
      }
    }
  }
}

// ---------------- FUSED MLP: out = h + GELU(ln2 @ W1^T + b1) @ W2^T + b2 ----------------
// Per 64-row block, loop 6 hidden-chunks of 64: stage W1-chunk + W2-chunk, m1 MFMA,
// bias+GELU -> bf16 act chunk in LDS, m2 MFMA accumulate. m1act never hits HBM.
__global__ __launch_bounds__(256) void k_mlp(const short* __restrict__ A,    // ln2, window order
                                             const short* __restrict__ W1,   // [384][128]
                                             const float* __restrict__ b1,
                                             const short* __restrict__ W2,   // [128][384]
                                             const float* __restrict__ b2,
                                             float* __restrict__ outF) {     // holds h; -> h+mlp
  __shared__ __attribute__((aligned(16))) short sW1[64][136];   // 17408 B
  __shared__ __attribute__((aligned(16))) short sW2[128][72];   // 18432 B
  __shared__ __attribute__((aligned(16))) short sAct[64][72];   //  9216 B
  const int t = threadIdx.x;
  const int wave = t >> 6, lane = t & 63;
  const int l15 = lane & 15, g = lane >> 4;
  const int m_base = blockIdx.x * 64 + wave * 16;
  const int kb = g * 8;

  // A-frags (ln2 rows, window order)
  bf16x8 af[4];
  #pragma unroll
  for (int s = 0; s < 4; ++s)
    af[s] = *(const bf16x8*)(A + (size_t)(m_base + l15) * Cn + s * 32 + kb);

  f32x4 acc2[8];
  #pragma unroll
  for (int tt = 0; tt < 8; ++tt) acc2[tt] = (f32x4){0.f, 0.f, 0.f, 0.f};

  for (int nb = 0; nb < 6; ++nb) {
    __syncthreads();   // protect sW1/sW2 from previous iteration's readers
    // stage W1 chunk: hidden rows nb*64.., all 128 k
    #pragma unroll
    for (int i = 0; i < 4; ++i) {
      int idx = i * 256 + t;
      int n = idx >> 4, kk = (idx & 15) * 8;
      *(bf16x8*)(&sW1[n][kk]) = *(const bf16x8*)(W1 + (size_t)(nb * 64 + n) * Cn + kk);
    }
    // stage W2 chunk: all 128 out-rows, k cols nb*64..
    #pragma unroll
    for (int i = 0; i < 4; ++i) {
      int idx = i * 256 + t;
      int n = idx >> 3, kk = (idx & 7) * 8;
      *(bf16x8*)(&sW2[n][kk]) = *(const bf16x8*)(W2 + (size_t)n * HID + nb * 64 + kk);
    }
    __syncthreads();

    // m1 chunk: 64 rows x 64 hidden cols
    f32x4 acc1[4];
    #pragma unroll
    for (int tt = 0; tt < 4; ++tt) acc1[tt] = (f32x4){0.f, 0.f, 0.f, 0.f};
    #pragma unroll
    for (int s = 0; s < 4; ++s) {
      #pragma unroll
      for (int tt = 0; tt < 4; ++tt) {
        bf16x8 bfr = *(const bf16x8*)(&sW1[tt * 16 + l15][s * 32 + kb]);
        acc1[tt] = __builtin_amdgcn_mfma_f32_16x16x32_bf16(af[s], bfr, acc1[tt], 0, 0, 0);
      }
    }
    // bias + tanh-GELU -> act chunk (bf16). Row (block-local) = wave*16+4g+r.
    #pragma unroll
    for (int tt = 0; tt < 4; ++tt) {
      float bb = b1[nb * 64 + tt * 16 + l15];
      #pragma unroll
      for (int r = 0; r < 4; ++r) {
        float v = acc1[tt][r] + bb;
        float u = v + 0.044715f * v * v * v;
        float e = __expf(1.5957691216f * u);     // exp(2*sqrt(2/pi)*u)
        float th = 1.f - 2.f / (e + 1.f);
        sAct[wave * 16 + 4 * g + r][tt * 16 + l15] = f2bf(0.5f * v * (1.f + th));
      }
    }
    // same-wave act rows only -> lgkmcnt wait (compiler) suffices; no barrier here.
    // m2 partial: acc2 += act_chunk @ W2_chunk^T
    bf16x8 af2[2];
    #pragma unroll
    for (int sl = 0; sl < 2; ++sl)
      af2[sl] = *(const bf16x8*)(&sAct[wave * 16 + l15][sl * 32 + kb]);
    #pragma unroll
    for (int sl = 0; sl < 2; ++sl) {
      #pragma unroll
      for (int tt = 0; tt < 8; ++tt) {
        bf16x8 bfr = *(const bf16x8*)(&sW2[tt * 16 + l15][sl * 32 + kb]);
        acc2[tt] = __builtin_amdgcn_mfma_f32_16x16x32_bf16(af2[sl], bfr, acc2[tt], 0, 0, 0);
      }
    }
  }

  // epilogue (once): out = h + acc2 + b2. h loaded here (not prefetched) to keep VGPR low.
  size_t off3[4];
  float ov[4][8];
  #pragma unroll
  for (int r = 0; r < 4; ++r) {
    int m = m_base + 4 * g + r;
    off3[r] = (size_t)m * Cn + l15;
    #pragma unroll
    for (int c = 0; c < 8; ++c) ov[r][c] = outF[off3[r] + c * 16];
  }
  #pragma unroll
  for (int tt = 0; tt < 8; ++tt) {
    float bb = b2[tt * 16 + l15];
    #pragma unroll
    for (int r = 0; r < 4; ++r)
      outF[off3[r] + tt * 16] = ov[r][tt] + acc2[tt][r] + bb;
  }
}

// ---------------- proj GEMM + un-window + roll + residual + fused LN2 ----------------
__global__ __launch_bounds__(256) void k_proj(const short* __restrict__ A,
                                              const short* __restrict__ W,
                                              const float* __restrict__ bias,
                                              const float* __restrict__ x,
                                              const float* __restrict__ g2,
                                              const float* __restrict__ be2,
                                              float* __restrict__ hOut,
                                              short* __restrict__ lnOut) {
  __shared__ __attribute__((aligned(16))) short ldsW[128 * 128];   // 32 KB, XOR-swizzled
  const int t = threadIdx.x;
  const int wave = t >> 6, lane = t & 63;
  const int l15 = lane & 15, g = lane >> 4;
  const int m_base = blockIdx.x * 64 + wave * 16;
  const int kb = g * 8;

  // per-r plain offsets + prefetch ALL x residual values (overlaps staging/MFMA)
  size_t off[4];
  float xv[4][8];
  #pragma unroll
  for (int r = 0; r < 4; ++r) {
    int m = m_base + 4 * g + r;
    off[r] = plain_off(m, l15);
    #pragma unroll
    for (int c = 0; c < 8; ++c) xv[r][c] = x[off[r] + c * 16];
  }

  float bv[8], gv[8], bev[8];
  #pragma unroll
  for (int c = 0; c < 8; ++c) {
    bv[c] = bias[c * 16 + l15]; gv[c] = g2[c * 16 + l15]; bev[c] = be2[c * 16 + l15];
  }

  const int arow = m_base + l15;
  const int awin = arow / NTOK, atok = arow - awin * NTOK;
  const short* abase = A + (size_t)awin * 3 * NTOK * Cn + (size_t)atok * Cn;
  bf16x8 af[4];
  #pragma unroll
  for (int s = 0; s < 4; ++s)
    af[s] = *(const bf16x8*)(abase + s * 32 + kb);

  #pragma unroll
  for (int i = 0; i < 8; ++i) {
    int idx = i * 256 + t;
    int n = idx >> 4, gr = idx & 15;
    *(bf16x8*)(&ldsW[n * 128 + ((gr ^ (n & 7)) << 3)]) =
        *(const bf16x8*)(W + (size_t)n * Cn + gr * 8);
  }
  __syncthreads();

  f32x4 acc[8];
  #pragma unroll
  for (int tt = 0; tt < 8; ++tt) acc[tt] = (f32x4){0.f, 0.f, 0.f, 0.f};
  #pragma unroll
  for (int s = 0; s < 4; ++s) {
    #pragma unroll
    for (int tt = 0; tt < 8; ++tt) {
      int row = tt * 16 + l15;
      bf16x8 bfr = *(const bf16x8*)(&ldsW[row * 128 + (((s * 4 + g) ^ (l15 & 7)) << 3)]);
      acc[tt] = __builtin_amdgcn_mfma_f32_16x16x32_bf16(af[s], bfr, acc[tt], 0, 0, 0);
    }
  }

  #pragma unroll
  for (int r = 0; r < 4; ++r) {
    float hv[8];
    float s1 = 0.f, s2 = 0.f;
    #pragma unroll
    for (int tt = 0; tt < 8; ++tt) {
      hv[tt] = acc[tt][r] + bv[tt] + xv[r][tt];
      s1 += hv[tt];
      s2 += hv[tt] * hv[tt];
    }
    #pragma unroll
    for (int o = 8; o >= 1; o >>= 1) { s1 += __shfl_xor(s1, o); s2 += __shfl_xor(s2, o); }
    float mean = s1 * (1.f / Cn);
    float var  = s2 * (1.f / Cn) - mean * mean;
    float rstd = rsqrtf(var + 1e-5f);
    #pragma unroll
    for (int tt = 0; tt < 8; ++tt) {
      hOut[off[r] + tt * 16] = hv[tt];                                           // f32, plain
      lnOut[off[r] + tt * 16] = f2bf((hv[tt] - mean) * rstd * gv[tt] + bev[tt]); // bf16, plain
    }
  }
}

// ---------------- MFMA window attention (O written in-place to q-slot) ----------------
__global__ __launch_bounds__(256, 3) void k_attn(const short* __restrict__ qkv,
                                                 short* __restrict__ out) {
  __shared__ __attribute__((aligned(16))) short sVT[8192];      // 16 KB
  __shared__ __attribute__((aligned(16))) short sP[4][4096];    // 32 KB
  const int t = threadIdx.x;
  const int wave = t >> 6, lane = t & 63;
  const int l15 = lane & 15, g = lane >> 4;
  const int h = wave;
  const int win = blockIdx.x;
  const short* baseQ = qkv + (size_t)win * 3 * NTOK * Cn;
  const short* baseK = baseQ + NTOK * Cn;
  const short* baseV = baseK + NTOK * Cn;

  for (int i = t; i < NTOK * 16; i += 256) {
    int j = i >> 4, cb = (i & 15) * 8;
    int jj = j >> 3, u = j & 7;
    bf16x8 v = *(const bf16x8*)(baseV + (size_t)j * Cn + cb);
    #pragma unroll
    for (int uu = 0; uu < 8; ++uu) {
      int c = cb + uu;
      sVT[(c >> 4) * 1024 + (c & 15) * 64 + ((jj ^ (c & 7)) << 3) + u] = v[uu];
    }
  }
  for (int i = t; i < 128 * 15; i += 256) {
    int c = i / 15, j = 49 + i % 15;
    sVT[(c >> 4) * 1024 + (c & 15) * 64 + (((j >> 3) ^ (c & 7)) << 3) + (j & 7)] = 0;
  }

  bf16x8 aq[4], bk[4];
  #pragma unroll
  for (int mi = 0; mi < 4; ++mi)
    aq[mi] = *(const bf16x8*)(baseQ + (size_t)(mi * 16 + l15) * Cn + h * 32 + g * 8);
  #pragma unroll
  for (int ni = 0; ni < 4; ++ni)
    bk[ni] = *(const bf16x8*)(baseK + (size_t)(ni * 16 + l15) * Cn + h * 32 + g * 8);

  f32x4 s[4][4];
  #pragma unroll
  for (int mi = 0; mi < 4; ++mi)
    #pragma unroll
    for (int ni = 0; ni < 4; ++ni) {
      s[mi][ni] = (f32x4){0.f, 0.f, 0.f, 0.f};
      s[mi][ni] = __builtin_amdgcn_mfma_f32_16x16x32_bf16(aq[mi], bk[ni], s[mi][ni], 0, 0, 0);
    }

  const float SC = 0.17677669529663687f;   // 1/sqrt(32)
  #pragma unroll
  for (int mi = 0; mi < 4; ++mi) {
    #pragma unroll
    for (int r = 0; r < 4; ++r) {
      float a0 = s[mi][0][r] * SC, a1 = s[mi][1][r] * SC, a2 = s[mi][2][r] * SC;
      float a3 = (l15 == 0) ? s[mi][3][r] * SC : -1e30f;   // col 48 only valid one
      float m = fmaxf(fmaxf(a0, a1), fmaxf(a2, a3));
      #pragma unroll
      for (int o = 8; o >= 1; o >>= 1) m = fmaxf(m, __shfl_xor(m, o));
      float e0 = __expf(a0 - m), e1 = __expf(a1 - m), e2 = __expf(a2 - m);
      float e3 = (l15 == 0) ? __expf(a3 - m) : 0.f;
      float ss = e0 + e1 + e2 + e3;
      #pragma unroll
      for (int o = 8; o >= 1; o >>= 1) ss += __shfl_xor(ss, o);
      float inv = 1.f / ss;
      int rr = 4 * g + r;
      float ee[4] = {e0, e1, e2, e3};
      #pragma unroll
      for (int ni = 0; ni < 4; ++ni) {
        int col = 16 * ni + l15;
        sP[wave][(mi * 2 + (col >> 5)) * 512 + rr * 32 + (((col >> 3) & 3) * 8) + (col & 7)]
            = f2bf(ee[ni] * inv);
      }
    }
  }

  __syncthreads();   // VT visible; also drains global reads before in-place store

  f32x4 o_[4][2];
  #pragma unroll
  for (int mi = 0; mi < 4; ++mi)
    #pragma unroll
    for (int ni = 0; ni < 2; ++ni) o_[mi][ni] = (f32x4){0.f, 0.f, 0.f, 0.f};

  #pragma unroll
  for (int ks = 0; ks < 2; ++ks) {
    bf16x8 bv[2];
    #pragma unroll
    for (int ni = 0; ni < 2; ++ni)
      bv[ni] = *(const bf16x8*)(&sVT[(h * 2 + ni) * 1024 + l15 * 64 +
                                     (((ks * 4 + g) ^ (l15 & 7)) << 3)]);
    #pragma unroll
    for (int mi = 0; mi < 4; ++mi) {
      bf16x8 ap = *(const bf16x8*)(&sP[wave][(mi * 2 + ks) * 512 + l15 * 32 + g * 8]);
      #pragma unroll
      for (int ni = 0; ni < 2; ++ni)
        o_[mi][ni] = __builtin_amdgcn_mfma_f32_16x16x32_bf16(ap, bv[ni], o_[mi][ni], 0, 0, 0);
    }
  }

  #pragma unroll
  for (int mi = 0; mi < 4; ++mi) {
    #pragma unroll
    for (int r = 0; r < 4; ++r) {
      int i = 16 * mi + 4 * g + r;
      if (i < NTOK) {
        short* orow = out + ((size_t)win * 3 * NTOK + i) * Cn + h * 32;
        #pragma unroll
        for (int ni = 0; ni < 2; ++ni)
          orow[16 * ni + l15] = f2bf(o_[mi][ni][r]);
      }
    }
  }
}

extern "C" void kernel_launch(void* const* d_in, const int* in_sizes, int n_in,
                              void* d_out, int out_size, void* d_ws, size_t ws_size,
                              hipStream_t stream) {
  const float* x     = (const float*)d_in[0];
  const float* g1    = (const float*)d_in[1];
  const float* be1   = (const float*)d_in[2];
  const float* Wqkv  = (const float*)d_in[3];
  const float* bqkv  = (const float*)d_in[4];
  const float* Wproj = (const float*)d_in[5];
  const float* bproj = (const float*)d_in[6];
  const float* g2    = (const float*)d_in[7];
  const float* be2   = (const float*)d_in[8];
  const float* Wm1   = (const float*)d_in[9];
  const float* bm1   = (const float*)d_in[10];
  const float* Wm2   = (const float*)d_in[11];
  const float* bm2   = (const float*)d_in[12];
  float* out = (float*)d_out;

  char* ws = (char*)d_ws;
  size_t SA = (size_t)Mtot * Cn * 2;    // 51.4 MB: ln1win / ln2 (plain)
  size_t SB = (size_t)Mtot * HID * 2;   // 154.1 MB: qkv
  short* bufA = (short*)ws;
  short* bufB = (short*)(ws + SA);
  short* wq = (short*)(ws + SA + SB);
  short* wp = wq + 384 * 128;
  short* w1 = wp + 128 * 128;
  short* w2 = w1 + 384 * 128;

  k_cvt4<<<640, 256, 0, stream>>>(Wqkv, Wproj, Wm1, Wm2, wq, wp, w1, w2);

  k_ln1<<<Mtot / 4, 256, 0, stream>>>(x, g1, be1, bufA);
  k_qkvg<<<Mtot / 64, 256, 0, stream>>>(bufA, wq, bqkv, bufB);
  k_attn<<<NWIN, 256, 0, stream>>>(bufB, bufB);
  k_proj<<<Mtot / 64, 256, 0, stream>>>(bufB, wp, bproj, x, g2, be2, out, bufA);
  k_mlp<<<Mtot / 64, 256, 0, stream>>>(bufA, w1, bm1, w2, bm2, out);
}